// Round 3
// baseline (166.869 us; speedup 1.0000x reference)
//
#include <hip/hip_runtime.h>

// RegL1Loss: out[b] = sum_{p,d} valid * |preds[b, idx[b,p,d]] - val| / num_people[b]
// B=32, P=64, D=34, L=1048576. gts layout [B,P,D,3] = (val, idx, flag).
//
// Single fused kernel. One block per image (32 blocks x 1024 threads = 16
// waves/CU on 32 CUs). Wave handles 4 persons: 16 lanes/person, each lane
// covers dims {sl, sl+16, sl+32} -> <=3 independent gathers, fully pipelined.
// Per-person: 16-lane butterfly sum + ballot nibble for any-valid.
// Block: 64-slot LDS reduce by wave 0, direct write to d_out. No d_ws, one
// launch -> removes second kernel + ws round trip from the timed region.

#define B_ 32
#define P_ 64
#define D_ 34
#define L_ 1048576

__global__ __launch_bounds__(1024) void reg_l1_fused(
    const float* __restrict__ preds,
    const float* __restrict__ gts,
    float* __restrict__ out) {
  const int b    = blockIdx.x;
  const int tid  = threadIdx.x;
  const int wave = tid >> 6;        // 0..15
  const int lane = tid & 63;
  const int lg   = lane >> 4;       // person-within-wave 0..3
  const int sl   = lane & 15;       // sub-lane 0..15
  const int p    = wave * 4 + lg;   // person 0..63

  const float* pred_b = preds + (size_t)b * L_;
  const float* gt_p   = gts + (((size_t)b * P_ + p) * D_) * 3;

  float contrib = 0.0f;
  int valid = 0;
  // dims sl, sl+16, sl+32 — independent loads, compiler pipelines them
  #pragma unroll
  for (int d = sl; d < D_; d += 16) {
    const float v    = gt_p[d * 3 + 0];
    const float fidx = gt_p[d * 3 + 1];
    const float flag = gt_p[d * 3 + 2];
    if (flag > 0.0f) {
      contrib += fabsf(pred_b[(int)fidx] - v);
      valid = 1;
    }
  }

  // 16-lane butterfly within the person group.
  contrib += __shfl_xor(contrib, 1);
  contrib += __shfl_xor(contrib, 2);
  contrib += __shfl_xor(contrib, 4);
  contrib += __shfl_xor(contrib, 8);
  // Per-person any-valid: extract this group's 16-bit nibble of the ballot.
  const unsigned long long bal = __ballot(valid);
  const int any = ((bal >> (lg * 16)) & 0xFFFFull) != 0ull;

  __shared__ float s_sum[P_];
  __shared__ float s_cnt[P_];
  if (sl == 0) {
    s_sum[p] = contrib;
    s_cnt[p] = (float)any;
  }
  __syncthreads();

  if (tid < 64) {
    float s = s_sum[tid];
    float c = s_cnt[tid];
    for (int off = 1; off < 64; off <<= 1) {
      s += __shfl_xor(s, off);
      c += __shfl_xor(c, off);
    }
    if (tid == 0) out[b] = s / c;   // >=1 valid person guaranteed by setup
  }
}

extern "C" void kernel_launch(void* const* d_in, const int* in_sizes, int n_in,
                              void* d_out, int out_size, void* d_ws, size_t ws_size,
                              hipStream_t stream) {
  const float* preds = (const float*)d_in[0];  // [B, L]
  const float* gts   = (const float*)d_in[1];  // [B, P, D, 3]
  float* out = (float*)d_out;                  // [B]
  reg_l1_fused<<<B_, 1024, 0, stream>>>(preds, gts, out);
}